// Round 4
// baseline (1552.830 us; speedup 1.0000x reference)
//
#include <hip/hip_runtime.h>

typedef __attribute__((ext_vector_type(8))) short bf16x8;
typedef __attribute__((ext_vector_type(4))) float f32x4;

__device__ __forceinline__ short f2bf(float f) {
  union { float f; unsigned u; } v; v.f = f;
  unsigned r = v.u + 0x7fffu + ((v.u >> 16) & 1u);
  return (short)(r >> 16);
}
__device__ __forceinline__ float sigm(float x) {
  float e = exp2f(-1.44269504f * x);
  return __builtin_amdgcn_rcpf(1.0f + e);
}
__device__ __forceinline__ float tanh_f(float x) {
  float a = __builtin_fabsf(x);
  float t = exp2f(-2.88539008f * a);
  float r = (1.0f - t) * __builtin_amdgcn_rcpf(1.0f + t);
  return __builtin_copysignf(r, x);
}
__device__ __forceinline__ f32x4 splat4(float b){ f32x4 v = {b,b,b,b}; return v; }

// ws layout (shorts for wp):
//  R1  [16 mem][4 nf][8 kc][64 l][8 e]  W_hh1 packed  (512KB)
//  R2a [16][2 gh][8 kc][64][8]          W_ih2         (256KB)
//  R2b [16][2][4][64][8]                W_hh2         (128KB)
//  R1i [16][4][8][64][8]                W_ih1         (512KB)
#define R1S   0
#define R2AS  262144
#define R2BS  393216
#define R1IS  458752
#define CTRL_B 1441792   // claim[xcd] @ dword xcd*32 ; per-(group,wave) ctrs from dword 256
#define H0X_B  1462272   // [2][16 grp][256 row][256 u] bf16 = 4MB
#define H1X_B  5656576   // [2][16 grp][256 row][128 u] bf16 = 2MB

// gate-pair packing: tile col = ul*2 + gp ; gate = gh*2 + gp
__global__ __launch_bounds__(256) void pack_w(
    const float* __restrict__ W_ih1, const float* __restrict__ W_hh1,
    const float* __restrict__ W_ih2, const float* __restrict__ W_hh2,
    short* __restrict__ wp) {
  int s = blockIdx.x * 256 + threadIdx.x;
  if (blockIdx.x == 0) {   // zero 20KB control region each launch
    unsigned* c = (unsigned*)((char*)wp + CTRL_B);
    #pragma unroll
    for (int k = 0; k < 20; ++k) c[threadIdx.x + k * 256] = 0u;
  }
  if (s >= 90112) return;
  const float* src; int row, K, k0, l;
  if (s < 32768) {            // R1 <- W_hh1 [1024][256]
    int mm = s >> 11, r = s & 2047, nf = r >> 9, kc = (r >> 6) & 7; l = r & 63;
    int a = nf >> 1, gh = nf & 1, ul = (l & 15) >> 1, gp = l & 1;
    row = (gh*2+gp)*256 + mm*16 + a*8 + ul; K = 256; k0 = kc*32 + (l>>4)*8; src = W_hh1;
  } else if (s < 49152) {     // R2a <- W_ih2 [512][256]
    int s2 = s - 32768, mm = s2 >> 10, r = s2 & 1023, gh = r >> 9, kc = (r >> 6) & 7; l = r & 63;
    int ul = (l & 15) >> 1, gp = l & 1;
    row = (gh*2+gp)*128 + mm*8 + ul; K = 256; k0 = kc*32 + (l>>4)*8; src = W_ih2;
  } else if (s < 57344) {     // R2b <- W_hh2 [512][128]
    int s3 = s - 49152, mm = s3 >> 9, r = s3 & 511, gh = r >> 8, kc = (r >> 6) & 3; l = r & 63;
    int ul = (l & 15) >> 1, gp = l & 1;
    row = (gh*2+gp)*128 + mm*8 + ul; K = 128; k0 = kc*32 + (l>>4)*8; src = W_hh2;
  } else {                    // R1i <- W_ih1 [1024][256]
    int s4 = s - 57344, mm = s4 >> 11, r = s4 & 2047, nf = r >> 9, kc = (r >> 6) & 7; l = r & 63;
    int a = nf >> 1, gh = nf & 1, ul = (l & 15) >> 1, gp = l & 1;
    row = (gh*2+gp)*256 + mm*16 + a*8 + ul; K = 256; k0 = kc*32 + (l>>4)*8; src = W_ih1;
  }
  const float* p = src + (size_t)row * K + k0;
  bf16x8 o;
  #pragma unroll
  for (int e = 0; e < 8; ++e) o[e] = f2bf(p[e]);
  *(bf16x8*)(wp + (size_t)s * 8) = o;
}

// 256 blocks x 512 threads, 1 block/CU (LDS-padded -> exactly 32 blocks/XCD).
// 16 groups x 16 members, 256 rows/group. Wave w of every member touches ONLY
// rows [32w,32w+32) -> per-(group,wave) barrier counters, NO syncthreads in loop.
// Iter u: layer1(u) -> arriveA(u) | waitB(u-2),load a1 | layer2(u-1) -> arriveB(u-1)
//         | waitA(u),load a0 | nt-store out(u-1).
__global__ __launch_bounds__(512, 2) void lstm_persist(
    const float* __restrict__ emb, const float* __restrict__ b_ih1,
    const float* __restrict__ b_hh1, const float* __restrict__ b_ih2,
    const float* __restrict__ b_hh2, char* __restrict__ ws,
    float* __restrict__ out) {
  extern __shared__ __align__(16) short ldsW[];
  const short* wp = (const short*)ws;
  unsigned* ctrl = (unsigned*)(ws + CTRL_B);
  __shared__ unsigned s_gm;
  const int tid = threadIdx.x, w = tid >> 6, l = tid & 63, l15 = l & 15, l4 = l >> 4;
  const int ul = l15 >> 1, gp = l15 & 1;

  // claim a (group, member) slot on this block's own XCD -> same-XCD groups
  if (tid == 0) {
    unsigned xcc;
    asm volatile("s_getreg_b32 %0, hwreg(HW_REG_XCC_ID)" : "=s"(xcc));
    xcc &= 7u;
    unsigned slot = atomicAdd(&ctrl[xcc * 32], 1u);
    s_gm = ((xcc * 2u + ((slot >> 4) & 1u)) << 8) | (slot & 15u);
  }
  __syncthreads();
  const int group = s_gm >> 8, member = s_gm & 255;

  // copy this member's weight slices into LDS (56KB)
  {
    const char* wpB = (const char*)wp;
    #pragma unroll
    for (int it = 0; it < 7; ++it) {
      int byte = (tid + it * 512) * 16;
      const char* src;
      if (byte < 32768)      src = wpB + (size_t)R1S * 2  + member * 32768 + byte;
      else if (byte < 49152) src = wpB + (size_t)R2AS * 2 + member * 16384 + (byte - 32768);
      else                   src = wpB + (size_t)R2BS * 2 + member * 8192  + (byte - 49152);
      *(f32x4*)((char*)ldsW + byte) = *(const f32x4*)src;
    }
  }
  float b2[2];
  #pragma unroll
  for (int gh = 0; gh < 2; ++gh) {
    int rw = (gh*2+gp)*128 + member*8 + ul;
    b2[gh] = b_ih2[rw] + b_hh2[rw];
  }
  float b1[4];
  #pragma unroll
  for (int nf = 0; nf < 4; ++nf) {
    int rw = ((nf&1)*2+gp)*256 + member*16 + (nf>>1)*8 + ul;
    b1[nf] = b_ih1[rw] + b_hh1[rw];
  }
  __syncthreads();   // LDS weights ready (last syncthreads before loop)

  // x1 = emb @ W_ih1^T + b1 for rows [group*256 + w*32, +32), kept in registers
  const int grow0 = group * 256;
  const int rw0 = w * 32;
  f32x4 x1[2][4];
  #pragma unroll
  for (int m = 0; m < 2; ++m)
    #pragma unroll
    for (int nf = 0; nf < 4; ++nf) x1[m][nf] = splat4(b1[nf]);
  #pragma unroll
  for (int kc = 0; kc < 8; ++kc) {
    bf16x8 af[2];
    #pragma unroll
    for (int m = 0; m < 2; ++m) {
      const float* ep = emb + (size_t)(grow0 + rw0 + m*16 + l15) * 256 + kc*32 + l4*8;
      f32x4 lo = *(const f32x4*)ep, hi = *(const f32x4*)(ep + 4);
      bf16x8 t8;
      #pragma unroll
      for (int e = 0; e < 4; ++e) { t8[e] = f2bf(lo[e]); t8[e+4] = f2bf(hi[e]); }
      af[m] = t8;
    }
    #pragma unroll
    for (int nf = 0; nf < 4; ++nf) {
      bf16x8 bb = *(const bf16x8*)(wp + R1IS + (((size_t)member*4 + nf)*8 + kc)*512 + l*8);
      x1[0][nf] = __builtin_amdgcn_mfma_f32_16x16x32_bf16(af[0], bb, x1[0][nf], 0, 0, 0);
      x1[1][nf] = __builtin_amdgcn_mfma_f32_16x16x32_bf16(af[1], bb, x1[1][nf], 0, 0, 0);
    }
  }

  bf16x8 a0[2][8], a1[2][4];
  const bf16x8 ZB = {0,0,0,0,0,0,0,0};
  #pragma unroll
  for (int m = 0; m < 2; ++m) {
    #pragma unroll
    for (int kc = 0; kc < 8; ++kc) a0[m][kc] = ZB;
    #pragma unroll
    for (int kc = 0; kc < 4; ++kc) a1[m][kc] = ZB;
  }
  float c0[2][2][2] = {};   // [m][a][rr]
  float c1[2][2] = {};      // [m][rr]
  float hout[2][2];         // carried to out-store at end of iter

  unsigned* ctrA = &ctrl[256 + (group * 8 + w) * 32];
  unsigned* ctrB = ctrA + 16;
  char* h0x = ws + H0X_B;
  char* h1x = ws + H1X_B;

  #pragma unroll 1
  for (int u = 0; u <= 128; ++u) {
    // ============ layer1(u): x1 + h0(u-1) @ W_hh1^T ============
    if (u < 128) {
      f32x4 acc1[2][4];
      #pragma unroll
      for (int m = 0; m < 2; ++m)
        #pragma unroll
        for (int nf = 0; nf < 4; ++nf) acc1[m][nf] = x1[m][nf];
      #pragma unroll
      for (int nf = 0; nf < 4; ++nf)
        #pragma unroll
        for (int kc = 0; kc < 8; ++kc) {
          bf16x8 bb = *(const bf16x8*)(ldsW + (nf*8 + kc)*512 + l*8);
          acc1[0][nf] = __builtin_amdgcn_mfma_f32_16x16x32_bf16(a0[0][kc], bb, acc1[0][nf], 0,0,0);
          acc1[1][nf] = __builtin_amdgcn_mfma_f32_16x16x32_bf16(a0[1][kc], bb, acc1[1][nf], 0,0,0);
        }
      char* h0w = h0x + ((size_t)(u & 1) * 16 + group) * 131072;
      #pragma unroll
      for (int m = 0; m < 2; ++m)
        #pragma unroll
        for (int a = 0; a < 2; ++a) {
          f32x4 v0 = acc1[m][a*2+0], v1 = acc1[m][a*2+1];
          #pragma unroll
          for (int rr = 0; rr < 2; ++rr) {
            float s0 = gp ? v0[rr] : v0[2+rr];
            float s1 = gp ? v1[rr] : v1[2+rr];
            float p0 = __shfl_xor(s0, 1, 64);
            float p1 = __shfl_xor(s1, 1, 64);
            float o0 = gp ? v0[2+rr] : v0[rr];
            float o1 = gp ? v1[2+rr] : v1[rr];
            float iv = gp ? p0 : o0, fv = gp ? o0 : p0;
            float gv = gp ? p1 : o1, ov = gp ? o1 : p1;
            float c = sigm(fv) * c0[m][a][rr] + sigm(iv) * tanh_f(gv);
            c0[m][a][rr] = c;
            float h = sigm(ov) * tanh_f(c);
            int row = rw0 + m*16 + l4*4 + gp*2 + rr;
            *(short*)(h0w + row*512 + (member*16 + a*8 + ul)*2) = f2bf(h);
          }
        }
      asm volatile("s_waitcnt vmcnt(0)" ::: "memory");   // wave's h0 stores in L2
      if (l == 0)
        __hip_atomic_fetch_add(ctrA, 1u, __ATOMIC_RELAXED, __HIP_MEMORY_SCOPE_AGENT);
    }
    // ============ waitB(u-2) -> load a1 = h1(u-2) ============
    if (u >= 2) {
      unsigned tgt = 16u * (u - 1); int z = 0;
      while (__hip_atomic_load(ctrB, __ATOMIC_RELAXED, __HIP_MEMORY_SCOPE_AGENT) < tgt) {
        __builtin_amdgcn_s_sleep(1);
        if (++z > (1 << 18)) break;        // escape hatch: fail visibly, never hang
      }
      asm volatile("buffer_inv sc0\n\ts_waitcnt vmcnt(0)" ::: "memory");
      const char* h1r = h1x + ((size_t)((u - 2) & 1) * 16 + group) * 65536;
      #pragma unroll
      for (int m = 0; m < 2; ++m)
        #pragma unroll
        for (int kc = 0; kc < 4; ++kc)
          a1[m][kc] = *(const bf16x8*)(h1r + (rw0 + m*16 + l15)*256 + kc*64 + l4*16);
    }
    // ============ layer2(u-1): h0(u-1)@W_ih2^T + b2 + h1(u-2)@W_hh2^T ============
    if (u >= 1) {
      f32x4 acc2[2][2];
      #pragma unroll
      for (int m = 0; m < 2; ++m)
        #pragma unroll
        for (int gh = 0; gh < 2; ++gh) acc2[m][gh] = splat4(b2[gh]);
      #pragma unroll
      for (int gh = 0; gh < 2; ++gh)
        #pragma unroll
        for (int kc = 0; kc < 8; ++kc) {
          bf16x8 bb = *(const bf16x8*)(ldsW + 16384 + (gh*8 + kc)*512 + l*8);
          acc2[0][gh] = __builtin_amdgcn_mfma_f32_16x16x32_bf16(a0[0][kc], bb, acc2[0][gh], 0,0,0);
          acc2[1][gh] = __builtin_amdgcn_mfma_f32_16x16x32_bf16(a0[1][kc], bb, acc2[1][gh], 0,0,0);
        }
      #pragma unroll
      for (int gh = 0; gh < 2; ++gh)
        #pragma unroll
        for (int kc = 0; kc < 4; ++kc) {
          bf16x8 bb = *(const bf16x8*)(ldsW + 24576 + (gh*4 + kc)*512 + l*8);
          acc2[0][gh] = __builtin_amdgcn_mfma_f32_16x16x32_bf16(a1[0][kc], bb, acc2[0][gh], 0,0,0);
          acc2[1][gh] = __builtin_amdgcn_mfma_f32_16x16x32_bf16(a1[1][kc], bb, acc2[1][gh], 0,0,0);
        }
      char* h1w = h1x + ((size_t)((u - 1) & 1) * 16 + group) * 65536;
      #pragma unroll
      for (int m = 0; m < 2; ++m) {
        f32x4 v0 = acc2[m][0], v1 = acc2[m][1];
        #pragma unroll
        for (int rr = 0; rr < 2; ++rr) {
          float s0 = gp ? v0[rr] : v0[2+rr];
          float s1 = gp ? v1[rr] : v1[2+rr];
          float p0 = __shfl_xor(s0, 1, 64);
          float p1 = __shfl_xor(s1, 1, 64);
          float o0 = gp ? v0[2+rr] : v0[rr];
          float o1 = gp ? v1[2+rr] : v1[rr];
          float iv = gp ? p0 : o0, fv = gp ? o0 : p0;
          float gv = gp ? p1 : o1, ov = gp ? o1 : p1;
          float c = sigm(fv) * c1[m][rr] + sigm(iv) * tanh_f(gv);
          c1[m][rr] = c;
          float h = sigm(ov) * tanh_f(c);
          hout[m][rr] = h;
          if (u < 128) {
            int row = rw0 + m*16 + l4*4 + gp*2 + rr;
            *(short*)(h1w + row*256 + (member*8 + ul)*2) = f2bf(h);
          }
        }
      }
      asm volatile("s_waitcnt vmcnt(0)" ::: "memory");   // wave's h1 stores in L2
      if (l == 0)
        __hip_atomic_fetch_add(ctrB, 1u, __ATOMIC_RELAXED, __HIP_MEMORY_SCOPE_AGENT);
    }
    // ============ waitA(u) -> load a0 = h0(u) ============
    if (u < 128) {
      unsigned tgt = 16u * (u + 1); int z = 0;
      while (__hip_atomic_load(ctrA, __ATOMIC_RELAXED, __HIP_MEMORY_SCOPE_AGENT) < tgt) {
        __builtin_amdgcn_s_sleep(1);
        if (++z > (1 << 18)) break;
      }
      asm volatile("buffer_inv sc0\n\ts_waitcnt vmcnt(0)" ::: "memory");
      const char* h0r = h0x + ((size_t)(u & 1) * 16 + group) * 131072;
      #pragma unroll
      for (int m = 0; m < 2; ++m)
        #pragma unroll
        for (int kc = 0; kc < 8; ++kc)
          a0[m][kc] = *(const bf16x8*)(h0r + (rw0 + m*16 + l15)*512 + kc*64 + l4*16);
    }
    // ============ out(u-1) NT stores (issued last; drained 1+ phases later) ============
    if (u >= 1) {
      const int t = u - 1;
      #pragma unroll
      for (int m = 0; m < 2; ++m)
        #pragma unroll
        for (int rr = 0; rr < 2; ++rr) {
          int row = rw0 + m*16 + l4*4 + gp*2 + rr;
          __builtin_nontemporal_store(
              hout[m][rr], out + (size_t)(grow0 + row) * 16384 + t*128 + member*8 + ul);
        }
    }
  }
}

extern "C" void kernel_launch(void* const* d_in, const int* in_sizes, int n_in,
                              void* d_out, int out_size, void* d_ws, size_t ws_size,
                              hipStream_t stream) {
  const float* emb   = (const float*)d_in[0];
  const float* W_ih1 = (const float*)d_in[1];
  const float* W_hh1 = (const float*)d_in[2];
  const float* b_ih1 = (const float*)d_in[3];
  const float* b_hh1 = (const float*)d_in[4];
  const float* W_ih2 = (const float*)d_in[5];
  const float* W_hh2 = (const float*)d_in[6];
  const float* b_ih2 = (const float*)d_in[7];
  const float* b_hh2 = (const float*)d_in[8];
  char* ws = (char*)d_ws;
  float* out = (float*)d_out;

  hipFuncSetAttribute((const void*)lstm_persist,
                      hipFuncAttributeMaxDynamicSharedMemorySize, 98304);
  pack_w<<<352, 256, 0, stream>>>(W_ih1, W_hh1, W_ih2, W_hh2, (short*)d_ws);
  lstm_persist<<<256, 512, 98304, stream>>>(emb, b_ih1, b_hh1, b_ih2, b_hh2, ws, out);
}